// Round 8
// baseline (26.800 us; speedup 1.0000x reference)
//
#include <hip/hip_runtime.h>
#include <math.h>

#define N_GAUSS 2048
#define IMG_H 256
#define IMG_W 256
#define NPIX (IMG_H * IMG_W)
#define EPS 1e-4f

#define TILE 16                              // 16x16 pixel super-tile
#define TILES_X (IMG_W / TILE)               // 16
#define NTILES (TILES_X * (IMG_H / TILE))    // 256
#define NTHREADS 1024
#define NWAVES 16
#define SEG (N_GAUSS / NWAVES)               // 128 gaussians per wave-segment
// Half-diagonal of the 16x16 pixel-center extent: 7.5*sqrt(2)/256 = 0.0414320
#define D_HALF 0.041436f                     // strictly above the exact value

// Strict-< sorted-insert ladder; lowest index wins ties (top_k stable order).
#define LADDER(T, G)                                                     \
    if ((T) < v7) {                                                      \
        const bool c0 = (T) < v0, c1 = (T) < v1, c2 = (T) < v2;          \
        const bool c3 = (T) < v3, c4 = (T) < v4, c5 = (T) < v5;          \
        const bool c6 = (T) < v6;                                        \
        v7 = c6 ? v6 : (T);            i7 = c6 ? i6 : (G);               \
        v6 = c6 ? (c5 ? v5 : (T)) : v6; i6 = c6 ? (c5 ? i5 : (G)) : i6;  \
        v5 = c5 ? (c4 ? v4 : (T)) : v5; i5 = c5 ? (c4 ? i4 : (G)) : i5;  \
        v4 = c4 ? (c3 ? v3 : (T)) : v4; i4 = c4 ? (c3 ? i3 : (G)) : i4;  \
        v3 = c3 ? (c2 ? v2 : (T)) : v3; i3 = c3 ? (c2 ? i2 : (G)) : i3;  \
        v2 = c2 ? (c1 ? v1 : (T)) : v2; i2 = c2 ? (c1 ? i1 : (G)) : i2;  \
        v1 = c1 ? (c0 ? v0 : (T)) : v1; i1 = c1 ? (c0 ? i0 : (G)) : i1;  \
        v0 = c0 ? (T) : v0;            i0 = c0 ? (G) : i0;               \
    }

// values-only ladder (screening)
#define VLADDER(T)                                                       \
    if ((T) < v7) {                                                      \
        const bool c0 = (T) < v0, c1 = (T) < v1, c2 = (T) < v2;          \
        const bool c3 = (T) < v3, c4 = (T) < v4, c5 = (T) < v5;          \
        const bool c6 = (T) < v6;                                        \
        v7 = c6 ? v6 : (T);                                              \
        v6 = c6 ? (c5 ? v5 : (T)) : v6;                                  \
        v5 = c5 ? (c4 ? v4 : (T)) : v5;                                  \
        v4 = c4 ? (c3 ? v3 : (T)) : v4;                                  \
        v3 = c3 ? (c2 ? v2 : (T)) : v3;                                  \
        v2 = c2 ? (c1 ? v1 : (T)) : v2;                                  \
        v1 = c1 ? (c0 ? v0 : (T)) : v1;                                  \
        v0 = c0 ? (T) : v0;                                              \
    }

// Compare-exchange on constant-indexed array elems (registers after unroll).
#define CE(a, i, j)                                   \
    { float lo_ = fminf(a[i], a[j]);                  \
      float hi_ = fmaxf(a[i], a[j]);                  \
      a[i] = lo_; a[j] = hi_; }

// In-wave exact top-8 reduce: each lane holds an ascending 8-list (INF-padded);
// after 6 butterfly levels every lane holds the wave's exact sorted top-8.
// (Verbatim from the passing R6/R7 kernels.)
__device__ __forceinline__ void top8_butterfly(float (&cur)[8]) {
#pragma unroll
    for (int m = 1; m < 64; m <<= 1) {
        float oth[8];
#pragma unroll
        for (int k = 0; k < 8; ++k) oth[k] = __shfl_xor(cur[k], m, 64);
        float t_[8];
#pragma unroll
        for (int k = 0; k < 8; ++k) t_[k] = fminf(cur[k], oth[7 - k]);
        CE(t_,0,4) CE(t_,1,5) CE(t_,2,6) CE(t_,3,7)
        CE(t_,0,2) CE(t_,1,3) CE(t_,4,6) CE(t_,5,7)
        CE(t_,0,1) CE(t_,2,3) CE(t_,4,5) CE(t_,6,7)
#pragma unroll
        for (int k = 0; k < 8; ++k) cur[k] = t_[k];
    }
}

// Single fused kernel, one 16x16 super-tile per block:
//   A) fp32 conservative screen of all gaussians vs super-tile center
//   B) exact 8th-smallest bound via butterfly reduce (wave, then block)
//   C) ordered compaction fused with exact f64-trig staging into LDS
//   D) bit-exact per-pixel top-8 (4 sub-tiles x 4 candidate-quarters) + merge + blend
__launch_bounds__(NTHREADS)
__global__ void fused_kernel(const float* __restrict__ xy,
                             const float* __restrict__ scale,
                             const float* __restrict__ rot,
                             const float* __restrict__ feat,
                             float* __restrict__ out) {
    __shared__ float rlo[N_GAUSS];            // 8 KB: r(center)-m per gaussian
    __shared__ float wlist[NWAVES][8];        // per-wave sorted top-8 of rp
    __shared__ float s_cut;
    __shared__ unsigned short qidx[N_GAUSS];  // 4 KB: per-segment candidate ids
    __shared__ int qcnt[NWAVES];
    __shared__ float4 cps[N_GAUSS];           // 32 KB: staged x,y,cos,sin
    __shared__ float2 csc[N_GAUSS];           // 16 KB: staged sx,sy
    __shared__ float          lt[4][8][256];  // 32 KB: quarter-merge values
    __shared__ unsigned short li[4][8][256];  // 16 KB: quarter-merge indices

    const int tid  = threadIdx.x;
    const int lane = tid & 63;
    const int w    = tid >> 6;
    const int tile = blockIdx.x;
    const int tx   = tile & (TILES_X - 1);
    const int ty   = tile >> 4;

    // ---------------- Phase A: fp32 screen vs super-tile center ------------
    // |r(p)-r(c)| <= max(sx,sy)*||p-c|| <= m; approximate trig error is
    // absorbed by the 0.01 cut slack (same proof as the passing R4-R7).
    const float cx = (float)(tx * TILE + 8) * (1.0f / IMG_W);
    const float cy = (float)(ty * TILE + 8) * (1.0f / IMG_H);
    float cur[8];
    {
        float v0 = INFINITY, v1 = INFINITY, v2 = INFINITY, v3 = INFINITY;
        float v4 = INFINITY, v5 = INFINITY, v6 = INFINITY, v7 = INFINITY;
#pragma unroll
        for (int r = 0; r < N_GAUSS / NTHREADS; ++r) {   // 2 iterations
            int g = r * NTHREADS + tid;
            float2 xyg = ((const float2*)xy)[g];
            float2 scg = ((const float2*)scale)[g];
            float  rg  = rot[g];
            float s, c;
            __sincosf(rg, &s, &c);
            float dx = cx - xyg.x;
            float dy = cy - xyg.y;
            float lx = dx * c + dy * s;
            float ly = dy * c - dx * s;
            float a  = lx * scg.x;
            float b  = ly * scg.y;
            float rr = sqrtf(a * a + b * b);
            float m  = fmaxf(scg.x, scg.y) * D_HALF;
            rlo[g]   = rr - m;
            float rp = rr + m;
            VLADDER(rp)
        }
        cur[0] = v0; cur[1] = v1; cur[2] = v2; cur[3] = v3;
        cur[4] = v4; cur[5] = v5; cur[6] = v6; cur[7] = v7;
    }

    // ---------------- Phase B: exact global 8th-smallest bound -------------
    top8_butterfly(cur);                       // per-wave exact top-8
    if (lane == 0) {
#pragma unroll
        for (int k = 0; k < 8; ++k) wlist[w][k] = cur[k];
    }
    __syncthreads();

    if (w == 0) {
        // Wave 0 merges the 16 wave-lists; lanes >=16 contribute INF lists,
        // which are neutral -> result is the exact block-wide top-8.
        float cur2[8];
#pragma unroll
        for (int k = 0; k < 8; ++k)
            cur2[k] = (lane < NWAVES) ? wlist[lane][k] : INFINITY;
        top8_butterfly(cur2);
        if (lane == 0) {
            float cut = cur2[7];
            s_cut = cut + 0.01f + 1e-4f * cut;  // slack >> all error budgets
        }
    }
    __syncthreads();
    const float cut = s_cut;

    // ---------------- Phase C: ordered compaction + exact staging ----------
    // Wave w compacts its 128-gaussian segment (ascending index). The keeping
    // lane computes the exact params once: (float)cos((double)rot) is
    // bit-identical to the R2-R7 exact path.
    {
        const int segbase = w * SEG;
        unsigned base = 0;
        for (int s2 = 0; s2 < SEG / 64; ++s2) {   // 2 rounds
            int g = segbase + s2 * 64 + lane;
            bool keep = rlo[g] <= cut;
            unsigned long long mask = __ballot(keep);
            if (keep) {
                unsigned pos = base + (unsigned)__popcll(mask & ((1ull << lane) - 1ull));
                float2 xyg = ((const float2*)xy)[g];
                float2 scg = ((const float2*)scale)[g];
                double rg  = (double)rot[g];
                float cc = (float)cos(rg);
                float ss = (float)sin(rg);
                qidx[segbase + pos] = (unsigned short)g;
                cps[segbase + pos]  = make_float4(xyg.x, xyg.y, cc, ss);
                csc[segbase + pos]  = make_float2(scg.x, scg.y);
            }
            base += (unsigned)__popcll(mask);
        }
        if (lane == 0) qcnt[w] = (int)base;
    }
    __syncthreads();

    // ---------------- Phase D: bit-exact per-pixel top-8 -------------------
    // wave w: sub-tile st = w&3 (8x8 pixels = 64 lanes), candidate quarter
    // q = w>>2 (segments 4q..4q+3, ascending gaussian index).
    const int st = w & 3;
    const int q  = w >> 2;
    const int pxi = tx * TILE + (st & 1) * 8 + (lane & 7);
    const int pyi = ty * TILE + (st >> 1) * 8 + (lane >> 3);
    const int p   = pyi * IMG_W + pxi;
    const float px = (pxi + 0.5f) * (1.0f / IMG_W);
    const float py = (pyi + 0.5f) * (1.0f / IMG_H);

    float v0 = INFINITY, v1 = INFINITY, v2 = INFINITY, v3 = INFINITY;
    float v4 = INFINITY, v5 = INFINITY, v6 = INFINITY, v7 = INFINITY;
    int   i0 = 0, i1 = 0, i2 = 0, i3 = 0, i4 = 0, i5 = 0, i6 = 0, i7 = 0;

    for (int s = q * 4; s < q * 4 + 4; ++s) {
        const int sb  = s * SEG;
        const int cnt = qcnt[s];
        for (int j = 0; j < cnt; ++j) {
            float4 a4 = cps[sb + j];     // uniform addr -> LDS broadcast
            float2 b2 = csc[sb + j];
            int    g  = (int)qidx[sb + j];
            // Bit-exact reference arithmetic (one rounding per op, no fma):
            float dx = __fsub_rn(px, a4.x);
            float dy = __fsub_rn(py, a4.y);
            float lx = __fadd_rn(__fmul_rn(dx, a4.z), __fmul_rn(dy, a4.w));
            float ly = __fadd_rn(__fmul_rn(-dx, a4.w), __fmul_rn(dy, a4.z));
            float aa = __fmul_rn(lx, b2.x);
            float bb = __fmul_rn(ly, b2.y);
            float t2 = __fadd_rn(__fmul_rn(aa, aa), __fmul_rn(bb, bb));
            LADDER(t2, g)
        }
    }

    {
        const int pix = st * 64 + lane;
        lt[q][0][pix] = v0; li[q][0][pix] = (unsigned short)i0;
        lt[q][1][pix] = v1; li[q][1][pix] = (unsigned short)i1;
        lt[q][2][pix] = v2; li[q][2][pix] = (unsigned short)i2;
        lt[q][3][pix] = v3; li[q][3][pix] = (unsigned short)i3;
        lt[q][4][pix] = v4; li[q][4][pix] = (unsigned short)i4;
        lt[q][5][pix] = v5; li[q][5][pix] = (unsigned short)i5;
        lt[q][6][pix] = v6; li[q][6][pix] = (unsigned short)i6;
        lt[q][7][pix] = v7; li[q][7][pix] = (unsigned short)i7;
    }
    __syncthreads();

    // Waves 0..3 (quarter 0) merge the 4 quarter-lists for their own sub-tile
    // (st == w, so px/py/p above are already this wave's pixels). Ascending
    // quarter order == ascending gaussian index -> identical selection and
    // ordering to the single-stream ladder.
    if (w < 4) {
        v0 = INFINITY; v1 = INFINITY; v2 = INFINITY; v3 = INFINITY;
        v4 = INFINITY; v5 = INFINITY; v6 = INFINITY; v7 = INFINITY;
        i0 = 0; i1 = 0; i2 = 0; i3 = 0; i4 = 0; i5 = 0; i6 = 0; i7 = 0;
        const int pix = w * 64 + lane;
        for (int c = 0; c < 4; ++c) {
#pragma unroll
            for (int k = 0; k < 8; ++k) {
                float t2 = lt[c][k][pix];
                int   g  = (int)li[c][k][pix];
                LADDER(t2, g)
            }
        }
        float w0 = expf(-0.5f * v0), w1 = expf(-0.5f * v1);
        float w2 = expf(-0.5f * v2), w3 = expf(-0.5f * v3);
        float w4 = expf(-0.5f * v4), w5 = expf(-0.5f * v5);
        float w6 = expf(-0.5f * v6), w7 = expf(-0.5f * v7);
        float sum = w0 + w1 + w2 + w3 + w4 + w5 + w6 + w7;
        float inv = 1.0f / (sum + EPS);

        float oc0 = 0.f, oc1 = 0.f, oc2 = 0.f;
#define ACC(K)                                                  \
        {                                                       \
            float al = w##K * inv;                              \
            const float* f = feat + 3 * i##K;                   \
            oc0 = fmaf(al, f[0], oc0);                          \
            oc1 = fmaf(al, f[1], oc1);                          \
            oc2 = fmaf(al, f[2], oc2);                          \
        }
        ACC(0) ACC(1) ACC(2) ACC(3) ACC(4) ACC(5) ACC(6) ACC(7)
#undef ACC

        out[p]            = oc0;
        out[p + NPIX]     = oc1;
        out[p + 2 * NPIX] = oc2;
    }
}

extern "C" void kernel_launch(void* const* d_in, const int* in_sizes, int n_in,
                              void* d_out, int out_size, void* d_ws, size_t ws_size,
                              hipStream_t stream) {
    const float* xy    = (const float*)d_in[0];
    const float* scale = (const float*)d_in[1];
    const float* rot   = (const float*)d_in[2];
    const float* feat  = (const float*)d_in[3];
    float* out = (float*)d_out;

    fused_kernel<<<NTILES, NTHREADS, 0, stream>>>(xy, scale, rot, feat, out);
}